// Round 1
// baseline (449.419 us; speedup 1.0000x reference)
//
#include <hip/hip_runtime.h>
#include <hip/hip_bf16.h>
#include <hip/hip_fp16.h>

#define B_ 512
#define L_ 20
#define NS_ 16
#define EPS_ 32
#define H_ 128
#define V_ 100000
#define N_NODES (B_*NS_)   // 8192
#define N_EDGES (B_*EPS_)  // 16384
#define NV (V_-1)          // 99999

typedef _Float16 half8 __attribute__((ext_vector_type(8)));
typedef float floatx4 __attribute__((ext_vector_type(4)));

#define PITCH 136  // 128 f16 + 8 pad -> 272B row, 4-bank rotation, 2-way max (free)

// ---------------- K1: weight conversions + node feature gather ----------------
__global__ void k_prep(const int* __restrict__ items, const float* __restrict__ emb,
                       const float* __restrict__ Wg, const float* __restrict__ Whh,
                       const float* __restrict__ Wih, const float* __restrict__ W2,
                       const float* __restrict__ W1,
                       float* __restrict__ x, _Float16* __restrict__ WgT_h,
                       _Float16* __restrict__ Whh_h, _Float16* __restrict__ Wih_h,
                       _Float16* __restrict__ W2_h, _Float16* __restrict__ W1_h) {
  int i = blockIdx.x*256 + threadIdx.x;
  if (i < N_NODES*H_) {          // x = embedding[items]
    int n = i >> 7, h = i & 127;
    x[i] = emb[(size_t)items[n]*H_ + h];
    return;
  }
  i -= N_NODES*H_;
  if (i < H_*H_) { int j = i>>7, k = i&127; WgT_h[i] = (_Float16)Wg[k*H_ + j]; return; }
  i -= H_*H_;
  if (i < 3*H_*H_) { Whh_h[i] = (_Float16)Whh[i]; return; }
  i -= 3*H_*H_;
  if (i < 3*H_*H_) { Wih_h[i] = (_Float16)Wih[i]; return; }
  i -= 3*H_*H_;
  if (i < H_*H_) { W2_h[i] = (_Float16)W2[i]; return; }
  i -= H_*H_;
  if (i < H_*H_) { W1_h[i] = (_Float16)W1[i]; return; }
}

// ---------------- generic K=128 f16-MFMA GEMM: C[M,N] = A[M,128] * B[N,128]^T ----
// A fp32 (converted on load), B f16 row-major [N][128]. 64x64 block tile, 4 waves.
// B pointer switches to B1 for m-tiles >= switch_mt (used for the q1/q2 fused GEMM).
__global__ __launch_bounds__(256) void k_gemm128(
    const float* __restrict__ A, const _Float16* __restrict__ B0,
    const _Float16* __restrict__ B1, int switch_mt,
    float* __restrict__ C, int N) {
  __shared__ _Float16 lds_a[64*PITCH];
  __shared__ _Float16 lds_b[64*PITCH];
  const int tid = threadIdx.x;
  const int mt = blockIdx.y, nt = blockIdx.x;
  const _Float16* __restrict__ Bp = (mt < switch_mt) ? B0 : B1;
  // stage A (64x128 fp32 -> f16): 64 rows x 32 float4-chunks = 2048 = 8*256
  #pragma unroll
  for (int i = 0; i < 8; i++) {
    int lin = i*256 + tid;
    int row = lin >> 5, c4 = lin & 31;
    const float4 v = *reinterpret_cast<const float4*>(&A[(size_t)(mt*64+row)*H_ + c4*4]);
    union { _Float16 h[4]; uint2 u; } p;
    p.h[0]=(_Float16)v.x; p.h[1]=(_Float16)v.y; p.h[2]=(_Float16)v.z; p.h[3]=(_Float16)v.w;
    *reinterpret_cast<uint2*>(&lds_a[row*PITCH + c4*4]) = p.u;
  }
  // stage B (64x128 f16): 64 rows x 16 uint4-chunks = 1024 = 4*256
  #pragma unroll
  for (int i = 0; i < 4; i++) {
    int lin = i*256 + tid;
    int row = lin >> 4, ch = lin & 15;
    uint4 v = *reinterpret_cast<const uint4*>(&Bp[(size_t)(nt*64+row)*H_ + ch*8]);
    *reinterpret_cast<uint4*>(&lds_b[row*PITCH + ch*8]) = v;
  }
  __syncthreads();
  const int w = tid >> 6, lane = tid & 63, quad = lane >> 4, r16 = lane & 15;
  half8 afr[4];
  #pragma unroll
  for (int kk = 0; kk < 4; kk++)
    afr[kk] = *reinterpret_cast<const half8*>(&lds_a[(w*16 + r16)*PITCH + kk*32 + quad*8]);
  floatx4 acc[4];
  #pragma unroll
  for (int n4 = 0; n4 < 4; n4++) acc[n4] = (floatx4){0.f,0.f,0.f,0.f};
  #pragma unroll
  for (int n4 = 0; n4 < 4; n4++) {
    #pragma unroll
    for (int kk = 0; kk < 4; kk++) {
      half8 bfr = *reinterpret_cast<const half8*>(&lds_b[(n4*16 + r16)*PITCH + kk*32 + quad*8]);
      acc[n4] = __builtin_amdgcn_mfma_f32_16x16x32_f16(afr[kk], bfr, acc[n4], 0, 0, 0);
    }
  }
  #pragma unroll
  for (int n4 = 0; n4 < 4; n4++)
    #pragma unroll
    for (int r = 0; r < 4; r++) {
      int row = mt*64 + w*16 + quad*4 + r;
      int col = nt*64 + n4*16 + r16;
      C[(size_t)row*N + col] = acc[n4][r];
    }
}

// ---------------- K3fused: scatter-add + gi GEMM + GRU, one session per block ----
// Replaces k_scatter + k_gemm128(gi) + k_gru: kills agg/gi global round-trips.
// Block = 256 thr (4 waves); session b = 16 nodes. Wih read as B-frags straight
// from L2-hot global (98 KB total, no LDS staging needed).
#define GILP 385   // gi LDS pitch: 385%32==1 -> quad stride 4*385%32=4, 2-way max
__global__ __launch_bounds__(256) void k_gnn(
    const int* __restrict__ edge_index, const float* __restrict__ mgh,
    const _Float16* __restrict__ Wih, const float* __restrict__ b_ih,
    const float* __restrict__ b_hh, float* __restrict__ x) {
  __shared__ __align__(16) _Float16 a16[NS_*PITCH];
  __shared__ __align__(16) float gil[NS_*GILP];
  float* agg = gil;            // scratch alias; dead before gil is written
  const int b = blockIdx.x, tid = threadIdx.x;
  // scatter-add m (cols [0,128) of mgh) into agg; thread h owns column h of all
  // 16 rows -> race-free (edges are intra-session).
  if (tid < 128) {
    #pragma unroll
    for (int j = 0; j < NS_; j++) agg[j*128 + tid] = 0.f;
    for (int e = 0; e < EPS_; e++) {
      int se = edge_index[b*EPS_ + e];
      int de = edge_index[N_EDGES + b*EPS_ + e] - b*NS_;
      agg[de*128 + tid] += mgh[(size_t)se*512 + tid];
    }
  }
  __syncthreads();
  // convert agg -> f16 fragment tile
  #pragma unroll
  for (int j = 0; j < 8; j++) {
    int idx = j*256 + tid;
    a16[(idx >> 7)*PITCH + (idx & 127)] = (_Float16)agg[idx];
  }
  __syncthreads();
  // gi[16,384] = agg[16,128] @ Wih[384,128]^T ; wave w owns n-tiles w*6..w*6+5
  const int w = tid >> 6, lane = tid & 63, quad = lane >> 4, r16 = lane & 15;
  half8 afr[4];
  #pragma unroll
  for (int kk = 0; kk < 4; kk++)
    afr[kk] = *reinterpret_cast<const half8*>(&a16[r16*PITCH + kk*32 + quad*8]);
  floatx4 acc[6];
  #pragma unroll
  for (int t = 0; t < 6; t++) acc[t] = (floatx4){0.f,0.f,0.f,0.f};
  #pragma unroll
  for (int t = 0; t < 6; t++) {
    int g = w*6 + t;
    #pragma unroll
    for (int kk = 0; kk < 4; kk++) {
      half8 bfr = *reinterpret_cast<const half8*>(&Wih[(size_t)(g*16 + r16)*H_ + kk*32 + quad*8]);
      acc[t] = __builtin_amdgcn_mfma_f32_16x16x32_f16(afr[kk], bfr, acc[t], 0, 0, 0);
    }
  }
  #pragma unroll
  for (int t = 0; t < 6; t++)
    #pragma unroll
    for (int r = 0; r < 4; r++)
      gil[(quad*4 + r)*GILP + (w*6 + t)*16 + r16] = acc[t][r];
  __syncthreads();
  // GRU epilogue: x -> xg in place (2048 elems, 8 per thread)
  #pragma unroll
  for (int j = 0; j < 8; j++) {
    int idx = j*256 + tid;
    int nl = idx >> 7, h = idx & 127;
    size_t node = (size_t)b*NS_ + nl;
    float ir  = gil[nl*GILP + h]       + b_ih[h];
    float iz  = gil[nl*GILP + 128 + h] + b_ih[128 + h];
    float in_ = gil[nl*GILP + 256 + h] + b_ih[256 + h];
    float hr  = mgh[node*512 + 128 + h] + b_hh[h];
    float hz  = mgh[node*512 + 256 + h] + b_hh[128 + h];
    float hn  = mgh[node*512 + 384 + h] + b_hh[256 + h];
    float rr = 1.f/(1.f + __expf(-(ir + hr)));
    float zz = 1.f/(1.f + __expf(-(iz + hz)));
    float nn = tanhf(in_ + rr*hn);
    x[node*H_ + h] = (1.f - zz)*nn + zz*x[node*H_ + h];
  }
}

// ---------------- K6: ragged gather -> Hbuf rows [0,10240)=hidden, [10240,10752)=ht
__global__ void k_hidden(const int* __restrict__ items, const int* __restrict__ sequence,
                         const int* __restrict__ mask, const float* __restrict__ xg,
                         const float* __restrict__ emb, float* __restrict__ Hbuf) {
  int tid = threadIdx.x;
  int r = blockIdx.x*2 + (tid >> 7);
  int h = tid & 127;
  int b, l;
  if (r < B_*L_) { b = r / L_; l = r - b*L_; }
  else {
    b = r - B_*L_;
    int len = 0;
    for (int i = 0; i < L_; i++) len += mask[b*L_ + i];
    l = len - 1;
  }
  int seqv = sequence[b*L_ + l];
  float val = 0.f;
  if (seqv != 0) {
    int idx = -1;
    #pragma unroll
    for (int j = 0; j < NS_; j++) { if (idx < 0 && items[b*NS_ + j] == seqv) idx = j; }
    val = (idx >= 0) ? xg[(size_t)(b*NS_ + idx)*H_ + h] : emb[(size_t)seqv*H_ + h];
  }
  Hbuf[(size_t)r*H_ + h] = val;
}

// ---------------- K8: attention pool + hybrid transform + layernorm -> a_h (f16) --
__global__ __launch_bounds__(128) void k_attn(
    const float* __restrict__ Hbuf, const float* __restrict__ q,
    const float* __restrict__ b1, const float* __restrict__ b2,
    const float* __restrict__ w3, const float* __restrict__ Wt,
    const float* __restrict__ bt, const float* __restrict__ gamma,
    const float* __restrict__ beta, _Float16* __restrict__ a_h) {
  __shared__ float red[2];
  __shared__ float cat[256];
  const int b = blockIdx.x, t = threadIdx.x;
  float q1b = q[(size_t)(B_*L_ + b)*H_ + t] + b1[t] + b2[t];
  float w3t = w3[t];
  float at = 0.f;
  for (int l = 0; l < L_; l++) {
    float s = q1b + q[(size_t)(b*L_ + l)*H_ + t];
    float v = (1.f/(1.f + __expf(-s))) * w3t;
    #pragma unroll
    for (int o = 32; o > 0; o >>= 1) v += __shfl_down(v, o);
    if ((t & 63) == 0) red[t >> 6] = v;
    __syncthreads();
    float alpha = red[0] + red[1];
    __syncthreads();
    at += alpha * Hbuf[(size_t)(b*L_ + l)*H_ + t];  // hidden==0 at masked positions
  }
  float htv = Hbuf[(size_t)(B_*L_ + b)*H_ + t];
  cat[t] = at; cat[128 + t] = htv;
  __syncthreads();
  float hyb = bt[t];
  const float* wrow = &Wt[(size_t)t*256];
  #pragma unroll 4
  for (int k = 0; k < 256; k++) hyb += cat[k]*wrow[k];
  // layernorm over 128
  float s = hyb;
  #pragma unroll
  for (int o = 32; o > 0; o >>= 1) s += __shfl_down(s, o);
  if ((t & 63) == 0) red[t >> 6] = s;
  __syncthreads();
  float mu = (red[0] + red[1]) * (1.f/128.f);
  __syncthreads();
  float d = hyb - mu;
  float s2 = d*d;
  #pragma unroll
  for (int o = 32; o > 0; o >>= 1) s2 += __shfl_down(s2, o);
  if ((t & 63) == 0) red[t >> 6] = s2;
  __syncthreads();
  float var = (red[0] + red[1]) * (1.f/128.f);
  float y = d * rsqrtf(var + 1e-5f) * gamma[t] + beta[t];
  a_h[(size_t)b*H_ + t] = (_Float16)y;
}

// ---------------- K9: scores = a * emb[1:]^T  [512, 99999] fp32 out --------------
// 1D grid, XCD-grouped: the 4 mg-blocks sharing one emb B-tile get dispatch ids
// congruent mod 8 within a 32-block window -> same XCD (round-robin), concurrent
// misses merge -> 3 of 4 B-tile reads become that XCD's L2 hits.
__global__ __launch_bounds__(256) void k_scores(
    const _Float16* __restrict__ a_h, const float* __restrict__ emb,
    float* __restrict__ out) {
  __shared__ _Float16 lds_a[128*PITCH];
  __shared__ _Float16 lds_b[64*PITCH];
  const int tid = threadIdx.x;
  const int d = blockIdx.x;                 // 0..6271 (196 supergroups of 32)
  const int nt = (d >> 5)*8 + (d & 7);
  const int mg = (d >> 3) & 3;
  if (nt >= 1563) return;                   // 20 pad blocks, block-uniform exit
  // stage A: 128 rows x 128 f16 = 2048 uint4-chunks = 8*256
  #pragma unroll
  for (int i = 0; i < 8; i++) {
    int lin = i*256 + tid;
    int row = lin >> 4, ch = lin & 15;
    uint4 v = *reinterpret_cast<const uint4*>(&a_h[(size_t)(mg*128 + row)*H_ + ch*8]);
    *reinterpret_cast<uint4*>(&lds_a[row*PITCH + ch*8]) = v;
  }
  // stage B: 64 emb rows fp32 -> f16 (guard last tile): 2048 float4-chunks
  #pragma unroll
  for (int i = 0; i < 8; i++) {
    int lin = i*256 + tid;
    int row = lin >> 5, c4 = lin & 31;
    int g = nt*64 + row;
    float4 v = {0.f, 0.f, 0.f, 0.f};
    if (g < NV) v = *reinterpret_cast<const float4*>(&emb[(size_t)(1 + g)*H_ + c4*4]);
    union { _Float16 h[4]; uint2 u; } p;
    p.h[0]=(_Float16)v.x; p.h[1]=(_Float16)v.y; p.h[2]=(_Float16)v.z; p.h[3]=(_Float16)v.w;
    *reinterpret_cast<uint2*>(&lds_b[row*PITCH + c4*4]) = p.u;
  }
  __syncthreads();
  const int w = tid >> 6, lane = tid & 63, quad = lane >> 4, r16 = lane & 15;
  half8 afr[2][4];
  #pragma unroll
  for (int ms = 0; ms < 2; ms++)
    #pragma unroll
    for (int kk = 0; kk < 4; kk++)
      afr[ms][kk] = *reinterpret_cast<const half8*>(&lds_a[(w*32 + ms*16 + r16)*PITCH + kk*32 + quad*8]);
  floatx4 acc[2][4];
  #pragma unroll
  for (int ms = 0; ms < 2; ms++)
    #pragma unroll
    for (int n4 = 0; n4 < 4; n4++) acc[ms][n4] = (floatx4){0.f,0.f,0.f,0.f};
  #pragma unroll
  for (int n4 = 0; n4 < 4; n4++) {
    #pragma unroll
    for (int kk = 0; kk < 4; kk++) {
      half8 bfr = *reinterpret_cast<const half8*>(&lds_b[(n4*16 + r16)*PITCH + kk*32 + quad*8]);
      acc[0][n4] = __builtin_amdgcn_mfma_f32_16x16x32_f16(afr[0][kk], bfr, acc[0][n4], 0, 0, 0);
      acc[1][n4] = __builtin_amdgcn_mfma_f32_16x16x32_f16(afr[1][kk], bfr, acc[1][n4], 0, 0, 0);
    }
  }
  #pragma unroll
  for (int ms = 0; ms < 2; ms++)
    #pragma unroll
    for (int n4 = 0; n4 < 4; n4++)
      #pragma unroll
      for (int r = 0; r < 4; r++) {
        int row = mg*128 + w*32 + ms*16 + quad*4 + r;
        int col = nt*64 + n4*16 + r16;
        if (col < NV) out[(size_t)row*NV + col] = acc[ms][n4][r];
      }
}

extern "C" void kernel_launch(void* const* d_in, const int* in_sizes, int n_in,
                              void* d_out, int out_size, void* d_ws, size_t ws_size,
                              hipStream_t stream) {
  const int*   items     = (const int*)d_in[0];
  const int*   edge_index= (const int*)d_in[1];
  const int*   sequence  = (const int*)d_in[2];
  const int*   mask      = (const int*)d_in[3];
  const float* emb       = (const float*)d_in[4];
  const float* ggnn_w    = (const float*)d_in[5];
  const float* W_ih      = (const float*)d_in[6];
  const float* W_hh      = (const float*)d_in[7];
  const float* b_ih      = (const float*)d_in[8];
  const float* b_hh      = (const float*)d_in[9];
  const float* W1        = (const float*)d_in[10];
  const float* b1        = (const float*)d_in[11];
  const float* W2        = (const float*)d_in[12];
  const float* b2        = (const float*)d_in[13];
  const float* w3        = (const float*)d_in[14];
  const float* Wt        = (const float*)d_in[15];
  const float* bt        = (const float*)d_in[16];
  const float* gamma     = (const float*)d_in[17];
  const float* beta      = (const float*)d_in[18];

  char* ws = (char*)d_ws;
  // buffer layout (time-multiplexed)
  float* x    = (float*)(ws + 0);              // 8192x128, becomes xg in-place
  float* mgh  = (float*)(ws + 4194304);        // 8192x512: [m | gh]
  float* q    = (float*)(ws + 4194304);        // reuses mgh region after k_gnn
  float* Hbuf = (float*)(ws + 20971520);       // 10752x128
  _Float16* a_h   = (_Float16*)(ws + 39059456);
  _Float16* WgT_h = (_Float16*)(ws + 39190528);
  _Float16* Whh_h = (_Float16*)(ws + 39223296); // contiguous after WgT_h (B = [WgT;Whh])
  _Float16* Wih_h = (_Float16*)(ws + 39321600);
  _Float16* W2_h  = (_Float16*)(ws + 39419904);
  _Float16* W1_h  = (_Float16*)(ws + 39452672);
  float* out = (float*)d_out;

  // K1: prep (x gather + f16 weight conversions)
  k_prep<<<4672, 256, 0, stream>>>(items, emb, ggnn_w, W_hh, W_ih, W2, W1,
                                   x, WgT_h, Whh_h, Wih_h, W2_h, W1_h);
  // K2: mgh = x * [WgT ; Whh]^T   (m and gh fused, N=512)
  k_gemm128<<<dim3(8, 128), 256, 0, stream>>>(x, WgT_h, WgT_h, 1 << 30, mgh, 512);
  // K3 (fused): scatter + gi-GEMM + GRU  (x -> xg in place)
  k_gnn<<<512, 256, 0, stream>>>(edge_index, mgh, Wih_h, b_ih, b_hh, x);
  // K4: hidden + ht rows
  k_hidden<<<5376, 256, 0, stream>>>(items, sequence, mask, x, emb, Hbuf);
  // K5: q = Hbuf * W2^T (rows<10240) / W1^T (ht rows); N=128
  k_gemm128<<<dim3(2, 168), 256, 0, stream>>>(Hbuf, W2_h, W1_h, 160, q, 128);
  // K6: attention pooling + hybrid + layernorm -> a_h (f16)
  k_attn<<<512, 128, 0, stream>>>(Hbuf, q, b1, b2, w3, Wt, bt, gamma, beta, a_h);
  // K7: scores = a * emb[1:]^T (XCD-grouped 1D grid)
  k_scores<<<6272, 256, 0, stream>>>(a_h, emb, out);
}

// Round 2
// 408.558 us; speedup vs baseline: 1.1000x; 1.1000x over previous
//
#include <hip/hip_runtime.h>
#include <hip/hip_bf16.h>
#include <hip/hip_fp16.h>

#define B_ 512
#define L_ 20
#define NS_ 16
#define EPS_ 32
#define H_ 128
#define V_ 100000
#define N_NODES (B_*NS_)   // 8192
#define N_EDGES (B_*EPS_)  // 16384
#define NV (V_-1)          // 99999

typedef _Float16 half8 __attribute__((ext_vector_type(8)));
typedef float floatx4 __attribute__((ext_vector_type(4)));

#define PITCH 136  // 128 f16 + 8 pad -> 272B row, 4-bank rotation, 2-way max (free)

// ---------------- K1: weight conversions + node feature gather ----------------
__global__ void k_prep(const int* __restrict__ items, const float* __restrict__ emb,
                       const float* __restrict__ Wg, const float* __restrict__ Whh,
                       const float* __restrict__ Wih, const float* __restrict__ W2,
                       const float* __restrict__ W1,
                       float* __restrict__ x, _Float16* __restrict__ WgT_h,
                       _Float16* __restrict__ Whh_h, _Float16* __restrict__ Wih_h,
                       _Float16* __restrict__ W2_h, _Float16* __restrict__ W1_h) {
  int i = blockIdx.x*256 + threadIdx.x;
  if (i < N_NODES*H_) {          // x = embedding[items]
    int n = i >> 7, h = i & 127;
    x[i] = emb[(size_t)items[n]*H_ + h];
    return;
  }
  i -= N_NODES*H_;
  if (i < H_*H_) { int j = i>>7, k = i&127; WgT_h[i] = (_Float16)Wg[k*H_ + j]; return; }
  i -= H_*H_;
  if (i < 3*H_*H_) { Whh_h[i] = (_Float16)Whh[i]; return; }
  i -= 3*H_*H_;
  if (i < 3*H_*H_) { Wih_h[i] = (_Float16)Wih[i]; return; }
  i -= 3*H_*H_;
  if (i < H_*H_) { W2_h[i] = (_Float16)W2[i]; return; }
  i -= H_*H_;
  if (i < H_*H_) { W1_h[i] = (_Float16)W1[i]; return; }
}

// ---------------- K2: generic K=128 f16-MFMA GEMM: C[M,N] = A[M,128]*B[N,128]^T --
__global__ __launch_bounds__(256) void k_gemm128(
    const float* __restrict__ A, const _Float16* __restrict__ B0,
    const _Float16* __restrict__ B1, int switch_mt,
    float* __restrict__ C, int N) {
  __shared__ _Float16 lds_a[64*PITCH];
  __shared__ _Float16 lds_b[64*PITCH];
  const int tid = threadIdx.x;
  const int mt = blockIdx.y, nt = blockIdx.x;
  const _Float16* __restrict__ Bp = (mt < switch_mt) ? B0 : B1;
  #pragma unroll
  for (int i = 0; i < 8; i++) {
    int lin = i*256 + tid;
    int row = lin >> 5, c4 = lin & 31;
    const float4 v = *reinterpret_cast<const float4*>(&A[(size_t)(mt*64+row)*H_ + c4*4]);
    union { _Float16 h[4]; uint2 u; } p;
    p.h[0]=(_Float16)v.x; p.h[1]=(_Float16)v.y; p.h[2]=(_Float16)v.z; p.h[3]=(_Float16)v.w;
    *reinterpret_cast<uint2*>(&lds_a[row*PITCH + c4*4]) = p.u;
  }
  #pragma unroll
  for (int i = 0; i < 4; i++) {
    int lin = i*256 + tid;
    int row = lin >> 4, ch = lin & 15;
    uint4 v = *reinterpret_cast<const uint4*>(&Bp[(size_t)(nt*64+row)*H_ + ch*8]);
    *reinterpret_cast<uint4*>(&lds_b[row*PITCH + ch*8]) = v;
  }
  __syncthreads();
  const int w = tid >> 6, lane = tid & 63, quad = lane >> 4, r16 = lane & 15;
  half8 afr[4];
  #pragma unroll
  for (int kk = 0; kk < 4; kk++)
    afr[kk] = *reinterpret_cast<const half8*>(&lds_a[(w*16 + r16)*PITCH + kk*32 + quad*8]);
  floatx4 acc[4];
  #pragma unroll
  for (int n4 = 0; n4 < 4; n4++) acc[n4] = (floatx4){0.f,0.f,0.f,0.f};
  #pragma unroll
  for (int n4 = 0; n4 < 4; n4++) {
    #pragma unroll
    for (int kk = 0; kk < 4; kk++) {
      half8 bfr = *reinterpret_cast<const half8*>(&lds_b[(n4*16 + r16)*PITCH + kk*32 + quad*8]);
      acc[n4] = __builtin_amdgcn_mfma_f32_16x16x32_f16(afr[kk], bfr, acc[n4], 0, 0, 0);
    }
  }
  #pragma unroll
  for (int n4 = 0; n4 < 4; n4++)
    #pragma unroll
    for (int r = 0; r < 4; r++) {
      int row = mt*64 + w*16 + quad*4 + r;
      int col = nt*64 + n4*16 + r16;
      C[(size_t)row*N + col] = acc[n4][r];
    }
}

// ---------------- K3: fused scatter-add + gi GEMM + GRU, one session per block ---
#define GILP 385   // gi LDS pitch: 385%32==1 -> quad stride 4*385%32=4, 2-way max
__global__ __launch_bounds__(256) void k_gnn(
    const int* __restrict__ edge_index, const float* __restrict__ mgh,
    const _Float16* __restrict__ Wih, const float* __restrict__ b_ih,
    const float* __restrict__ b_hh, float* __restrict__ x) {
  __shared__ __align__(16) _Float16 a16[NS_*PITCH];
  __shared__ __align__(16) float gil[NS_*GILP];
  float* agg = gil;            // scratch alias; dead before gil is written
  const int b = blockIdx.x, tid = threadIdx.x;
  if (tid < 128) {
    #pragma unroll
    for (int j = 0; j < NS_; j++) agg[j*128 + tid] = 0.f;
    for (int e = 0; e < EPS_; e++) {
      int se = edge_index[b*EPS_ + e];
      int de = edge_index[N_EDGES + b*EPS_ + e] - b*NS_;
      agg[de*128 + tid] += mgh[(size_t)se*512 + tid];
    }
  }
  __syncthreads();
  #pragma unroll
  for (int j = 0; j < 8; j++) {
    int idx = j*256 + tid;
    a16[(idx >> 7)*PITCH + (idx & 127)] = (_Float16)agg[idx];
  }
  __syncthreads();
  const int w = tid >> 6, lane = tid & 63, quad = lane >> 4, r16 = lane & 15;
  half8 afr[4];
  #pragma unroll
  for (int kk = 0; kk < 4; kk++)
    afr[kk] = *reinterpret_cast<const half8*>(&a16[r16*PITCH + kk*32 + quad*8]);
  floatx4 acc[6];
  #pragma unroll
  for (int t = 0; t < 6; t++) acc[t] = (floatx4){0.f,0.f,0.f,0.f};
  #pragma unroll
  for (int t = 0; t < 6; t++) {
    int g = w*6 + t;
    #pragma unroll
    for (int kk = 0; kk < 4; kk++) {
      half8 bfr = *reinterpret_cast<const half8*>(&Wih[(size_t)(g*16 + r16)*H_ + kk*32 + quad*8]);
      acc[t] = __builtin_amdgcn_mfma_f32_16x16x32_f16(afr[kk], bfr, acc[t], 0, 0, 0);
    }
  }
  #pragma unroll
  for (int t = 0; t < 6; t++)
    #pragma unroll
    for (int r = 0; r < 4; r++)
      gil[(quad*4 + r)*GILP + (w*6 + t)*16 + r16] = acc[t][r];
  __syncthreads();
  #pragma unroll
  for (int j = 0; j < 8; j++) {
    int idx = j*256 + tid;
    int nl = idx >> 7, h = idx & 127;
    size_t node = (size_t)b*NS_ + nl;
    float ir  = gil[nl*GILP + h]       + b_ih[h];
    float iz  = gil[nl*GILP + 128 + h] + b_ih[128 + h];
    float in_ = gil[nl*GILP + 256 + h] + b_ih[256 + h];
    float hr  = mgh[node*512 + 128 + h] + b_hh[h];
    float hz  = mgh[node*512 + 256 + h] + b_hh[128 + h];
    float hn  = mgh[node*512 + 384 + h] + b_hh[256 + h];
    float rr = 1.f/(1.f + __expf(-(ir + hr)));
    float zz = 1.f/(1.f + __expf(-(iz + hz)));
    float nn = tanhf(in_ + rr*hn);
    x[node*H_ + h] = (1.f - zz)*nn + zz*x[node*H_ + h];
  }
}

// ---------------- K4: fused per-session hidden gather + q-GEMM + attention + LN --
// Replaces k_hidden + k_gemm128(q) + k_attn. One block per session (256 thr).
// hidden kept in LDS (fp32 + f16 copy); q2 via MFMA vs L2-hot W2_h; q1 via fp32
// dot; alpha phase wave-parallel (wave w owns positions w*5..w*5+4, fp32 reduce).
__global__ __launch_bounds__(256) void k_sess(
    const int* __restrict__ items, const int* __restrict__ sequence,
    const int* __restrict__ mask, const float* __restrict__ xg,
    const float* __restrict__ emb,
    const _Float16* __restrict__ W2h, const _Float16* __restrict__ W1h,
    const float* __restrict__ b1, const float* __restrict__ b2,
    const float* __restrict__ w3, const float* __restrict__ Wt,
    const float* __restrict__ bt, const float* __restrict__ gamma,
    const float* __restrict__ beta, _Float16* __restrict__ a_h) {
  __shared__ float hid[21*H_];            // rows 0..19 = hidden, row 20 = ht
  __shared__ __align__(16) _Float16 a16[32*PITCH];  // f16 hidden (rows 20..31 = 0)
  __shared__ float qs[20*H_];             // q2 (no bias)
  __shared__ float q1full[H_];            // q1 + b1 + b2
  __shared__ float alphas[20];
  __shared__ float cat[256];
  __shared__ float red4[4];
  const int b = blockIdx.x, tid = threadIdx.x;
  // session length (wave-uniform)
  int len = 0;
  #pragma unroll
  for (int i = 0; i < L_; i++) len += mask[b*L_ + i];
  // gather hidden rows 0..19 (2 rows per pass, 128 threads each)
  #pragma unroll
  for (int j = 0; j < 10; j++) {
    int r = j*2 + (tid >> 7);
    int h = tid & 127;
    int seqv = sequence[b*L_ + r];
    float val = 0.f;
    if (seqv != 0) {
      int idx = -1;
      #pragma unroll
      for (int jj = 0; jj < NS_; jj++) { if (idx < 0 && items[b*NS_ + jj] == seqv) idx = jj; }
      val = (idx >= 0) ? xg[(size_t)(b*NS_ + idx)*H_ + h] : emb[(size_t)seqv*H_ + h];
    }
    hid[r*H_ + h] = val;
    a16[r*PITCH + h] = (_Float16)val;
  }
  // zero f16 pad rows 20..31 (1536 elems)
  #pragma unroll
  for (int j = 0; j < 6; j++) {
    int idx = j*256 + tid;
    a16[(20 + (idx >> 7))*PITCH + (idx & 127)] = (_Float16)0.f;
  }
  __syncthreads();
  if (tid < 128) hid[20*H_ + tid] = hid[(len-1)*H_ + tid];   // ht
  __syncthreads();
  // q2[20,128] = hidden @ W2^T  (M-tile 32, N=128, K=128); 16 MFMA per wave
  const int w = tid >> 6, lane = tid & 63, quad = lane >> 4, r16 = lane & 15;
  {
    half8 afr[2][4];
    #pragma unroll
    for (int mt = 0; mt < 2; mt++)
      #pragma unroll
      for (int kk = 0; kk < 4; kk++)
        afr[mt][kk] = *reinterpret_cast<const half8*>(&a16[(mt*16 + r16)*PITCH + kk*32 + quad*8]);
    floatx4 acc[2][2];
    #pragma unroll
    for (int mt = 0; mt < 2; mt++)
      #pragma unroll
      for (int nt = 0; nt < 2; nt++) acc[mt][nt] = (floatx4){0.f,0.f,0.f,0.f};
    #pragma unroll
    for (int nt = 0; nt < 2; nt++) {
      #pragma unroll
      for (int kk = 0; kk < 4; kk++) {
        half8 bfr = *reinterpret_cast<const half8*>(&W2h[(size_t)((w*2 + nt)*16 + r16)*H_ + kk*32 + quad*8]);
        acc[0][nt] = __builtin_amdgcn_mfma_f32_16x16x32_f16(afr[0][kk], bfr, acc[0][nt], 0, 0, 0);
        acc[1][nt] = __builtin_amdgcn_mfma_f32_16x16x32_f16(afr[1][kk], bfr, acc[1][nt], 0, 0, 0);
      }
    }
    #pragma unroll
    for (int mt = 0; mt < 2; mt++)
      #pragma unroll
      for (int nt = 0; nt < 2; nt++)
        #pragma unroll
        for (int r = 0; r < 4; r++) {
          int row = mt*16 + quad*4 + r;
          if (row < 20) qs[row*H_ + (w*2 + nt)*16 + r16] = acc[mt][nt][r];
        }
  }
  // q1[t] = b1+b2 + ht(fp32) . W1(f16 row t)
  if (tid < 128) {
    float s = b1[tid] + b2[tid];
    const half8* wrow = reinterpret_cast<const half8*>(&W1h[(size_t)tid*H_]);
    #pragma unroll
    for (int k8 = 0; k8 < 16; k8++) {
      half8 hv = wrow[k8];
      #pragma unroll
      for (int u = 0; u < 8; u++) s += hid[20*H_ + k8*8 + u] * (float)hv[u];
    }
    q1full[tid] = s;
  }
  __syncthreads();
  // alpha: wave w -> positions w*5 .. w*5+4 (fp32, one barrier total)
  for (int j = 0; j < 5; j++) {
    int l = w*5 + j;
    float v = 0.f;
    #pragma unroll
    for (int p = 0; p < 2; p++) {
      int t = lane + p*64;
      float s = q1full[t] + qs[l*H_ + t];
      v += (1.f/(1.f + __expf(-s))) * w3[t];
    }
    #pragma unroll
    for (int o = 32; o > 0; o >>= 1) v += __shfl_down(v, o);
    if (lane == 0) alphas[l] = v;
  }
  __syncthreads();
  // pooled a + cat
  if (tid < 128) {
    float af = 0.f;
    #pragma unroll
    for (int l = 0; l < L_; l++) af += alphas[l]*hid[l*H_ + tid];
    cat[tid] = af; cat[128 + tid] = hid[20*H_ + tid];
  }
  __syncthreads();
  // hybrid transform + layernorm
  float hyb = 0.f;
  if (tid < 128) {
    hyb = bt[tid];
    const float* wrow = &Wt[(size_t)tid*256];
    #pragma unroll 4
    for (int k = 0; k < 256; k++) hyb += cat[k]*wrow[k];
  }
  float s1 = (tid < 128) ? hyb : 0.f;
  #pragma unroll
  for (int o = 32; o > 0; o >>= 1) s1 += __shfl_down(s1, o);
  if (lane == 0) red4[w] = s1;
  __syncthreads();
  float mu = (red4[0] + red4[1] + red4[2] + red4[3]) * (1.f/128.f);
  __syncthreads();
  float d = (tid < 128) ? (hyb - mu) : 0.f;
  float s2 = d*d;
  #pragma unroll
  for (int o = 32; o > 0; o >>= 1) s2 += __shfl_down(s2, o);
  if (lane == 0) red4[w] = s2;
  __syncthreads();
  if (tid < 128) {
    float var = (red4[0] + red4[1] + red4[2] + red4[3]) * (1.f/128.f);
    float y = d * rsqrtf(var + 1e-5f) * gamma[tid] + beta[tid];
    a_h[(size_t)b*H_ + tid] = (_Float16)y;
  }
}

// ---------------- K5: scores = a * emb[1:]^T  [512, 99999] fp32 out --------------
// (R0-measured 2D grid restored: grid (1563 n-tiles, 4 m-groups of 128 rows))
__global__ __launch_bounds__(256) void k_scores(
    const _Float16* __restrict__ a_h, const float* __restrict__ emb,
    float* __restrict__ out) {
  __shared__ _Float16 lds_a[128*PITCH];
  __shared__ _Float16 lds_b[64*PITCH];
  const int tid = threadIdx.x;
  const int nt = blockIdx.x, mg = blockIdx.y;
  #pragma unroll
  for (int i = 0; i < 8; i++) {
    int lin = i*256 + tid;
    int row = lin >> 4, ch = lin & 15;
    uint4 v = *reinterpret_cast<const uint4*>(&a_h[(size_t)(mg*128 + row)*H_ + ch*8]);
    *reinterpret_cast<uint4*>(&lds_a[row*PITCH + ch*8]) = v;
  }
  #pragma unroll
  for (int i = 0; i < 8; i++) {
    int lin = i*256 + tid;
    int row = lin >> 5, c4 = lin & 31;
    int g = nt*64 + row;
    float4 v = {0.f, 0.f, 0.f, 0.f};
    if (g < NV) v = *reinterpret_cast<const float4*>(&emb[(size_t)(1 + g)*H_ + c4*4]);
    union { _Float16 h[4]; uint2 u; } p;
    p.h[0]=(_Float16)v.x; p.h[1]=(_Float16)v.y; p.h[2]=(_Float16)v.z; p.h[3]=(_Float16)v.w;
    *reinterpret_cast<uint2*>(&lds_b[row*PITCH + c4*4]) = p.u;
  }
  __syncthreads();
  const int w = tid >> 6, lane = tid & 63, quad = lane >> 4, r16 = lane & 15;
  half8 afr[2][4];
  #pragma unroll
  for (int ms = 0; ms < 2; ms++)
    #pragma unroll
    for (int kk = 0; kk < 4; kk++)
      afr[ms][kk] = *reinterpret_cast<const half8*>(&lds_a[(w*32 + ms*16 + r16)*PITCH + kk*32 + quad*8]);
  floatx4 acc[2][4];
  #pragma unroll
  for (int ms = 0; ms < 2; ms++)
    #pragma unroll
    for (int n4 = 0; n4 < 4; n4++) acc[ms][n4] = (floatx4){0.f,0.f,0.f,0.f};
  #pragma unroll
  for (int n4 = 0; n4 < 4; n4++) {
    #pragma unroll
    for (int kk = 0; kk < 4; kk++) {
      half8 bfr = *reinterpret_cast<const half8*>(&lds_b[(n4*16 + r16)*PITCH + kk*32 + quad*8]);
      acc[0][n4] = __builtin_amdgcn_mfma_f32_16x16x32_f16(afr[0][kk], bfr, acc[0][n4], 0, 0, 0);
      acc[1][n4] = __builtin_amdgcn_mfma_f32_16x16x32_f16(afr[1][kk], bfr, acc[1][n4], 0, 0, 0);
    }
  }
  #pragma unroll
  for (int ms = 0; ms < 2; ms++)
    #pragma unroll
    for (int n4 = 0; n4 < 4; n4++)
      #pragma unroll
      for (int r = 0; r < 4; r++) {
        int row = mg*128 + w*32 + ms*16 + quad*4 + r;
        int col = nt*64 + n4*16 + r16;
        if (col < NV) out[(size_t)row*NV + col] = acc[ms][n4][r];
      }
}

extern "C" void kernel_launch(void* const* d_in, const int* in_sizes, int n_in,
                              void* d_out, int out_size, void* d_ws, size_t ws_size,
                              hipStream_t stream) {
  const int*   items     = (const int*)d_in[0];
  const int*   edge_index= (const int*)d_in[1];
  const int*   sequence  = (const int*)d_in[2];
  const int*   mask      = (const int*)d_in[3];
  const float* emb       = (const float*)d_in[4];
  const float* ggnn_w    = (const float*)d_in[5];
  const float* W_ih      = (const float*)d_in[6];
  const float* W_hh      = (const float*)d_in[7];
  const float* b_ih      = (const float*)d_in[8];
  const float* b_hh      = (const float*)d_in[9];
  const float* W1        = (const float*)d_in[10];
  const float* b1        = (const float*)d_in[11];
  const float* W2        = (const float*)d_in[12];
  const float* b2        = (const float*)d_in[13];
  const float* w3        = (const float*)d_in[14];
  const float* Wt        = (const float*)d_in[15];
  const float* bt        = (const float*)d_in[16];
  const float* gamma     = (const float*)d_in[17];
  const float* beta      = (const float*)d_in[18];

  char* ws = (char*)d_ws;
  float* x    = (float*)(ws + 0);              // 8192x128, becomes xg in-place
  float* mgh  = (float*)(ws + 4194304);        // 8192x512: [m | gh]
  _Float16* a_h   = (_Float16*)(ws + 39059456);
  _Float16* WgT_h = (_Float16*)(ws + 39190528);
  _Float16* Whh_h = (_Float16*)(ws + 39223296); // contiguous after WgT_h (B = [WgT;Whh])
  _Float16* Wih_h = (_Float16*)(ws + 39321600);
  _Float16* W2_h  = (_Float16*)(ws + 39419904);
  _Float16* W1_h  = (_Float16*)(ws + 39452672);
  float* out = (float*)d_out;

  // K1: prep (x gather + f16 weight conversions)
  k_prep<<<4672, 256, 0, stream>>>(items, emb, ggnn_w, W_hh, W_ih, W2, W1,
                                   x, WgT_h, Whh_h, Wih_h, W2_h, W1_h);
  // K2: mgh = x * [WgT ; Whh]^T   (m and gh fused, N=512)
  k_gemm128<<<dim3(8, 128), 256, 0, stream>>>(x, WgT_h, WgT_h, 1 << 30, mgh, 512);
  // K3: fused scatter + gi-GEMM + GRU  (x -> xg in place)
  k_gnn<<<512, 256, 0, stream>>>(edge_index, mgh, Wih_h, b_ih, b_hh, x);
  // K4: fused hidden gather + q GEMM + attention + hybrid + LN -> a_h
  k_sess<<<512, 256, 0, stream>>>(items, sequence, mask, x, emb, W2_h, W1_h,
                                  b1, b2, w3, Wt, bt, gamma, beta, a_h);
  // K5: scores = a * emb[1:]^T (R0 2D grid)
  k_scores<<<dim3(1563, 4), 256, 0, stream>>>(a_h, emb, out);
}

// Round 3
// 406.588 us; speedup vs baseline: 1.1053x; 1.0048x over previous
//
#include <hip/hip_runtime.h>
#include <hip/hip_bf16.h>
#include <hip/hip_fp16.h>

#define B_ 512
#define L_ 20
#define NS_ 16
#define EPS_ 32
#define H_ 128
#define V_ 100000
#define N_NODES (B_*NS_)   // 8192
#define N_EDGES (B_*EPS_)  // 16384
#define NV (V_-1)          // 99999

typedef _Float16 half8 __attribute__((ext_vector_type(8)));
typedef float floatx4 __attribute__((ext_vector_type(4)));

#define PITCH 136  // 128 f16 + 8 pad -> 272B row, 4-bank rotation, 2-way max (free)
#define GILP 385   // gi LDS pitch (f32): 2-way max
#define MGP 516    // mgh LDS pitch (f32): quad stride 4*516%32=16 -> 2-way max

// ---------------- K1: weight conversions only ----------------
__global__ void k_prep(const float* __restrict__ Wg, const float* __restrict__ Whh,
                       const float* __restrict__ Wih, const float* __restrict__ W2,
                       const float* __restrict__ W1,
                       _Float16* __restrict__ WgT_h, _Float16* __restrict__ Whh_h,
                       _Float16* __restrict__ Wih_h, _Float16* __restrict__ W2_h,
                       _Float16* __restrict__ W1_h) {
  int i = blockIdx.x*256 + threadIdx.x;
  if (i < H_*H_) { int j = i>>7, k = i&127; WgT_h[i] = (_Float16)Wg[k*H_ + j]; return; }
  i -= H_*H_;
  if (i < 3*H_*H_) { Whh_h[i] = (_Float16)Whh[i]; return; }
  i -= 3*H_*H_;
  if (i < 3*H_*H_) { Wih_h[i] = (_Float16)Wih[i]; return; }
  i -= 3*H_*H_;
  if (i < H_*H_) { W2_h[i] = (_Float16)W2[i]; return; }
  i -= H_*H_;
  if (i < H_*H_) { W1_h[i] = (_Float16)W1[i]; return; }
}

// ---------------- K2: fused full GNN step, one session per block ----------------
// gather emb[items] -> LDS; mgh = x @ [WgT;Whh]^T (LDS only); scatter-add;
// gi = agg @ Wih^T; GRU -> xg. mgh/agg/gi never touch global memory.
__global__ __launch_bounds__(256) void k_gnn2(
    const int* __restrict__ items, const int* __restrict__ edge_index,
    const float* __restrict__ emb, const _Float16* __restrict__ Wgh,
    const _Float16* __restrict__ Wih, const float* __restrict__ b_ih,
    const float* __restrict__ b_hh, float* __restrict__ xg) {
  __shared__ float xf[NS_*H_];                       // 8 KB   (fp32 x, GRU h-input)
  __shared__ __align__(16) _Float16 x16[NS_*PITCH];  // 4.25 KB (f16 x, MFMA A)
  __shared__ float mghl[NS_*MGP];                    // 33 KB  [m(128) | gh(384)]
  __shared__ __align__(16) _Float16 a16[NS_*PITCH];  // 4.25 KB (f16 agg)
  __shared__ __align__(16) float gil[NS_*GILP];      // 24.6 KB (agg aliases head)
  float* agg = gil;   // dead before gil written (barrier-separated)
  const int b = blockIdx.x, tid = threadIdx.x;
  // 1. gather node features
  #pragma unroll
  for (int j = 0; j < 8; j++) {
    int idx = j*256 + tid;
    int n = idx >> 7, h = idx & 127;
    float v = emb[(size_t)items[b*NS_ + n]*H_ + h];
    xf[n*H_ + h] = v;
    x16[n*PITCH + h] = (_Float16)v;
  }
  __syncthreads();
  const int w = tid >> 6, lane = tid & 63, quad = lane >> 4, r16 = lane & 15;
  // 2. mghl[16,512] = x[16,128] @ Wgh[512,128]^T ; wave w owns n-tiles w*8..w*8+7
  {
    half8 afr[4];
    #pragma unroll
    for (int kk = 0; kk < 4; kk++)
      afr[kk] = *reinterpret_cast<const half8*>(&x16[r16*PITCH + kk*32 + quad*8]);
    floatx4 acc[8];
    #pragma unroll
    for (int t = 0; t < 8; t++) acc[t] = (floatx4){0.f,0.f,0.f,0.f};
    #pragma unroll
    for (int t = 0; t < 8; t++) {
      int g = w*8 + t;
      #pragma unroll
      for (int kk = 0; kk < 4; kk++) {
        half8 bfr = *reinterpret_cast<const half8*>(&Wgh[(size_t)(g*16 + r16)*H_ + kk*32 + quad*8]);
        acc[t] = __builtin_amdgcn_mfma_f32_16x16x32_f16(afr[kk], bfr, acc[t], 0, 0, 0);
      }
    }
    #pragma unroll
    for (int t = 0; t < 8; t++)
      #pragma unroll
      for (int r = 0; r < 4; r++)
        mghl[(quad*4 + r)*MGP + (w*8 + t)*16 + r16] = acc[t][r];
  }
  __syncthreads();
  // 3. scatter-add m (cols 0..127) into agg; thread h owns column h (race-free)
  if (tid < 128) {
    #pragma unroll
    for (int j = 0; j < NS_; j++) agg[j*H_ + tid] = 0.f;
    for (int e = 0; e < EPS_; e++) {
      int se = edge_index[b*EPS_ + e] - b*NS_;
      int de = edge_index[N_EDGES + b*EPS_ + e] - b*NS_;
      agg[de*H_ + tid] += mghl[se*MGP + tid];
    }
  }
  __syncthreads();
  // 4. agg -> f16
  #pragma unroll
  for (int j = 0; j < 8; j++) {
    int idx = j*256 + tid;
    a16[(idx >> 7)*PITCH + (idx & 127)] = (_Float16)agg[idx];
  }
  __syncthreads();
  // 5. gil[16,384] = agg @ Wih[384,128]^T ; wave w owns n-tiles w*6..w*6+5
  {
    half8 afr[4];
    #pragma unroll
    for (int kk = 0; kk < 4; kk++)
      afr[kk] = *reinterpret_cast<const half8*>(&a16[r16*PITCH + kk*32 + quad*8]);
    floatx4 acc[6];
    #pragma unroll
    for (int t = 0; t < 6; t++) acc[t] = (floatx4){0.f,0.f,0.f,0.f};
    #pragma unroll
    for (int t = 0; t < 6; t++) {
      int g = w*6 + t;
      #pragma unroll
      for (int kk = 0; kk < 4; kk++) {
        half8 bfr = *reinterpret_cast<const half8*>(&Wih[(size_t)(g*16 + r16)*H_ + kk*32 + quad*8]);
        acc[t] = __builtin_amdgcn_mfma_f32_16x16x32_f16(afr[kk], bfr, acc[t], 0, 0, 0);
      }
    }
    #pragma unroll
    for (int t = 0; t < 6; t++)
      #pragma unroll
      for (int r = 0; r < 4; r++)
        gil[(quad*4 + r)*GILP + (w*6 + t)*16 + r16] = acc[t][r];
  }
  __syncthreads();
  // 6. GRU epilogue -> xg
  #pragma unroll
  for (int j = 0; j < 8; j++) {
    int idx = j*256 + tid;
    int nl = idx >> 7, h = idx & 127;
    float ir  = gil[nl*GILP + h]       + b_ih[h];
    float iz  = gil[nl*GILP + 128 + h] + b_ih[128 + h];
    float in_ = gil[nl*GILP + 256 + h] + b_ih[256 + h];
    float hr  = mghl[nl*MGP + 128 + h] + b_hh[h];
    float hz  = mghl[nl*MGP + 256 + h] + b_hh[128 + h];
    float hn  = mghl[nl*MGP + 384 + h] + b_hh[256 + h];
    float rr = 1.f/(1.f + __expf(-(ir + hr)));
    float zz = 1.f/(1.f + __expf(-(iz + hz)));
    float nn = tanhf(in_ + rr*hn);
    float hp = xf[nl*H_ + h];
    xg[(size_t)(b*NS_ + nl)*H_ + h] = (1.f - zz)*nn + zz*hp;
  }
}

// ---------------- K3: fused per-session hidden gather + q-GEMM + attention + LN --
__global__ __launch_bounds__(256) void k_sess(
    const int* __restrict__ items, const int* __restrict__ sequence,
    const int* __restrict__ mask, const float* __restrict__ xg,
    const float* __restrict__ emb,
    const _Float16* __restrict__ W2h, const _Float16* __restrict__ W1h,
    const float* __restrict__ b1, const float* __restrict__ b2,
    const float* __restrict__ w3, const float* __restrict__ Wt,
    const float* __restrict__ bt, const float* __restrict__ gamma,
    const float* __restrict__ beta, _Float16* __restrict__ a_h) {
  __shared__ float hid[21*H_];            // rows 0..19 = hidden, row 20 = ht
  __shared__ __align__(16) _Float16 a16[32*PITCH];  // f16 hidden (rows 20..31 = 0)
  __shared__ float qs[20*H_];             // q2 (no bias)
  __shared__ float q1full[H_];            // q1 + b1 + b2
  __shared__ float alphas[20];
  __shared__ float cat[256];
  __shared__ float red4[4];
  const int b = blockIdx.x, tid = threadIdx.x;
  int len = 0;
  #pragma unroll
  for (int i = 0; i < L_; i++) len += mask[b*L_ + i];
  #pragma unroll
  for (int j = 0; j < 10; j++) {
    int r = j*2 + (tid >> 7);
    int h = tid & 127;
    int seqv = sequence[b*L_ + r];
    float val = 0.f;
    if (seqv != 0) {
      int idx = -1;
      #pragma unroll
      for (int jj = 0; jj < NS_; jj++) { if (idx < 0 && items[b*NS_ + jj] == seqv) idx = jj; }
      val = (idx >= 0) ? xg[(size_t)(b*NS_ + idx)*H_ + h] : emb[(size_t)seqv*H_ + h];
    }
    hid[r*H_ + h] = val;
    a16[r*PITCH + h] = (_Float16)val;
  }
  #pragma unroll
  for (int j = 0; j < 6; j++) {
    int idx = j*256 + tid;
    a16[(20 + (idx >> 7))*PITCH + (idx & 127)] = (_Float16)0.f;
  }
  __syncthreads();
  if (tid < 128) hid[20*H_ + tid] = hid[(len-1)*H_ + tid];   // ht
  __syncthreads();
  const int w = tid >> 6, lane = tid & 63, quad = lane >> 4, r16 = lane & 15;
  // q2[20,128] = hidden @ W2^T  (M-tile 32, N=128, K=128)
  {
    half8 afr[2][4];
    #pragma unroll
    for (int mt = 0; mt < 2; mt++)
      #pragma unroll
      for (int kk = 0; kk < 4; kk++)
        afr[mt][kk] = *reinterpret_cast<const half8*>(&a16[(mt*16 + r16)*PITCH + kk*32 + quad*8]);
    floatx4 acc[2][2];
    #pragma unroll
    for (int mt = 0; mt < 2; mt++)
      #pragma unroll
      for (int nt = 0; nt < 2; nt++) acc[mt][nt] = (floatx4){0.f,0.f,0.f,0.f};
    #pragma unroll
    for (int nt = 0; nt < 2; nt++) {
      #pragma unroll
      for (int kk = 0; kk < 4; kk++) {
        half8 bfr = *reinterpret_cast<const half8*>(&W2h[(size_t)((w*2 + nt)*16 + r16)*H_ + kk*32 + quad*8]);
        acc[0][nt] = __builtin_amdgcn_mfma_f32_16x16x32_f16(afr[0][kk], bfr, acc[0][nt], 0, 0, 0);
        acc[1][nt] = __builtin_amdgcn_mfma_f32_16x16x32_f16(afr[1][kk], bfr, acc[1][nt], 0, 0, 0);
      }
    }
    #pragma unroll
    for (int mt = 0; mt < 2; mt++)
      #pragma unroll
      for (int nt = 0; nt < 2; nt++)
        #pragma unroll
        for (int r = 0; r < 4; r++) {
          int row = mt*16 + quad*4 + r;
          if (row < 20) qs[row*H_ + (w*2 + nt)*16 + r16] = acc[mt][nt][r];
        }
  }
  // q1[t] = b1+b2 + ht(fp32) . W1(f16 row t)
  if (tid < 128) {
    float s = b1[tid] + b2[tid];
    const half8* wrow = reinterpret_cast<const half8*>(&W1h[(size_t)tid*H_]);
    #pragma unroll
    for (int k8 = 0; k8 < 16; k8++) {
      half8 hv = wrow[k8];
      #pragma unroll
      for (int u = 0; u < 8; u++) s += hid[20*H_ + k8*8 + u] * (float)hv[u];
    }
    q1full[tid] = s;
  }
  __syncthreads();
  // alpha: wave w -> positions w*5 .. w*5+4
  for (int j = 0; j < 5; j++) {
    int l = w*5 + j;
    float v = 0.f;
    #pragma unroll
    for (int p = 0; p < 2; p++) {
      int t = lane + p*64;
      float s = q1full[t] + qs[l*H_ + t];
      v += (1.f/(1.f + __expf(-s))) * w3[t];
    }
    #pragma unroll
    for (int o = 32; o > 0; o >>= 1) v += __shfl_down(v, o);
    if (lane == 0) alphas[l] = v;
  }
  __syncthreads();
  if (tid < 128) {
    float af = 0.f;
    #pragma unroll
    for (int l = 0; l < L_; l++) af += alphas[l]*hid[l*H_ + tid];
    cat[tid] = af; cat[128 + tid] = hid[20*H_ + tid];
  }
  __syncthreads();
  float hyb = 0.f;
  if (tid < 128) {
    hyb = bt[tid];
    const float* wrow = &Wt[(size_t)tid*256];
    #pragma unroll 4
    for (int k = 0; k < 256; k++) hyb += cat[k]*wrow[k];
  }
  float s1 = (tid < 128) ? hyb : 0.f;
  #pragma unroll
  for (int o = 32; o > 0; o >>= 1) s1 += __shfl_down(s1, o);
  if (lane == 0) red4[w] = s1;
  __syncthreads();
  float mu = (red4[0] + red4[1] + red4[2] + red4[3]) * (1.f/128.f);
  __syncthreads();
  float d = (tid < 128) ? (hyb - mu) : 0.f;
  float s2 = d*d;
  #pragma unroll
  for (int o = 32; o > 0; o >>= 1) s2 += __shfl_down(s2, o);
  if (lane == 0) red4[w] = s2;
  __syncthreads();
  if (tid < 128) {
    float var = (red4[0] + red4[1] + red4[2] + red4[3]) * (1.f/128.f);
    float y = d * rsqrtf(var + 1e-5f) * gamma[tid] + beta[tid];
    a_h[(size_t)b*H_ + tid] = (_Float16)y;
  }
}

// ---------------- K4: scores = a * emb[1:]^T  [512, 99999] fp32 out --------------
// grid 1563 nt-blocks x 512 thr (8 waves). M=512 in one block: emb tile read ONCE;
// A-fragments loaded directly from L2-resident a_h (128 KB), no LDS staging for A.
__global__ __launch_bounds__(512) void k_scores(
    const _Float16* __restrict__ a_h, const float* __restrict__ emb,
    float* __restrict__ out) {
  __shared__ _Float16 lds_b[64*PITCH];
  const int tid = threadIdx.x;
  const int nt = blockIdx.x;
  // stage B: 64 emb rows fp32 -> f16 (guard last tile): 2048 float4-chunks = 4*512
  #pragma unroll
  for (int i = 0; i < 4; i++) {
    int lin = i*512 + tid;
    int row = lin >> 5, c4 = lin & 31;
    int g = nt*64 + row;
    float4 v = {0.f, 0.f, 0.f, 0.f};
    if (g < NV) v = *reinterpret_cast<const float4*>(&emb[(size_t)(1 + g)*H_ + c4*4]);
    union { _Float16 h[4]; uint2 u; } p;
    p.h[0]=(_Float16)v.x; p.h[1]=(_Float16)v.y; p.h[2]=(_Float16)v.z; p.h[3]=(_Float16)v.w;
    *reinterpret_cast<uint2*>(&lds_b[row*PITCH + c4*4]) = p.u;
  }
  __syncthreads();
  const int w = tid >> 6, lane = tid & 63, quad = lane >> 4, r16 = lane & 15;
  floatx4 acc[4][4];
  #pragma unroll
  for (int ms = 0; ms < 4; ms++)
    #pragma unroll
    for (int n4 = 0; n4 < 4; n4++) acc[ms][n4] = (floatx4){0.f,0.f,0.f,0.f};
  #pragma unroll
  for (int ms = 0; ms < 4; ms++) {
    half8 afr[4];
    #pragma unroll
    for (int kk = 0; kk < 4; kk++)
      afr[kk] = *reinterpret_cast<const half8*>(&a_h[(size_t)(w*64 + ms*16 + r16)*H_ + kk*32 + quad*8]);
    #pragma unroll
    for (int n4 = 0; n4 < 4; n4++) {
      #pragma unroll
      for (int kk = 0; kk < 4; kk++) {
        half8 bfr = *reinterpret_cast<const half8*>(&lds_b[(n4*16 + r16)*PITCH + kk*32 + quad*8]);
        acc[ms][n4] = __builtin_amdgcn_mfma_f32_16x16x32_f16(afr[kk], bfr, acc[ms][n4], 0, 0, 0);
      }
    }
  }
  #pragma unroll
  for (int ms = 0; ms < 4; ms++)
    #pragma unroll
    for (int n4 = 0; n4 < 4; n4++)
      #pragma unroll
      for (int r = 0; r < 4; r++) {
        int row = w*64 + ms*16 + quad*4 + r;
        int col = nt*64 + n4*16 + r16;
        if (col < NV) out[(size_t)row*NV + col] = acc[ms][n4][r];
      }
}

extern "C" void kernel_launch(void* const* d_in, const int* in_sizes, int n_in,
                              void* d_out, int out_size, void* d_ws, size_t ws_size,
                              hipStream_t stream) {
  const int*   items     = (const int*)d_in[0];
  const int*   edge_index= (const int*)d_in[1];
  const int*   sequence  = (const int*)d_in[2];
  const int*   mask      = (const int*)d_in[3];
  const float* emb       = (const float*)d_in[4];
  const float* ggnn_w    = (const float*)d_in[5];
  const float* W_ih      = (const float*)d_in[6];
  const float* W_hh      = (const float*)d_in[7];
  const float* b_ih      = (const float*)d_in[8];
  const float* b_hh      = (const float*)d_in[9];
  const float* W1        = (const float*)d_in[10];
  const float* b1        = (const float*)d_in[11];
  const float* W2        = (const float*)d_in[12];
  const float* b2        = (const float*)d_in[13];
  const float* w3        = (const float*)d_in[14];
  const float* Wt        = (const float*)d_in[15];
  const float* bt        = (const float*)d_in[16];
  const float* gamma     = (const float*)d_in[17];
  const float* beta      = (const float*)d_in[18];

  char* ws = (char*)d_ws;
  float* x    = (float*)(ws + 0);              // 8192x128 xg (GRU output)
  _Float16* a_h   = (_Float16*)(ws + 39059456);
  _Float16* WgT_h = (_Float16*)(ws + 39190528);
  _Float16* Whh_h = (_Float16*)(ws + 39223296); // contiguous after WgT_h ([WgT;Whh])
  _Float16* Wih_h = (_Float16*)(ws + 39321600);
  _Float16* W2_h  = (_Float16*)(ws + 39419904);
  _Float16* W1_h  = (_Float16*)(ws + 39452672);
  float* out = (float*)d_out;

  // K1: f16 weight conversions (147456 elems = 576*256)
  k_prep<<<576, 256, 0, stream>>>(ggnn_w, W_hh, W_ih, W2, W1,
                                  WgT_h, Whh_h, Wih_h, W2_h, W1_h);
  // K2: full GNN step per session (gather + mgh-GEMM + scatter + gi-GEMM + GRU)
  k_gnn2<<<512, 256, 0, stream>>>(items, edge_index, emb, WgT_h, Wih_h,
                                  b_ih, b_hh, x);
  // K3: fused hidden gather + q GEMM + attention + hybrid + LN -> a_h
  k_sess<<<512, 256, 0, stream>>>(items, sequence, mask, x, emb, W2_h, W1_h,
                                  b1, b2, w3, Wt, bt, gamma, beta, a_h);
  // K4: scores = a * emb[1:]^T (single-pass M=512, emb read once)
  k_scores<<<1563, 512, 0, stream>>>(a_h, emb, out);
}

// Round 4
// 403.646 us; speedup vs baseline: 1.1134x; 1.0073x over previous
//
#include <hip/hip_runtime.h>
#include <hip/hip_bf16.h>
#include <hip/hip_fp16.h>

#define B_ 512
#define L_ 20
#define NS_ 16
#define EPS_ 32
#define H_ 128
#define V_ 100000
#define N_NODES (B_*NS_)   // 8192
#define N_EDGES (B_*EPS_)  // 16384
#define NV (V_-1)          // 99999

typedef _Float16 half8 __attribute__((ext_vector_type(8)));
typedef float floatx4 __attribute__((ext_vector_type(4)));

#define PITCH 136  // 128 f16 + 8 pad -> 272B row, 4-bank rotation, 2-way max (free)
#define GILP 385   // gi LDS pitch (f32): 2-way max
#define MGP 516    // mgh LDS pitch (f32): quad stride 4*516%32=16 -> 2-way max

// ---------------- K1: weight conversions only ----------------
__global__ void k_prep(const float* __restrict__ Wg, const float* __restrict__ Whh,
                       const float* __restrict__ Wih, const float* __restrict__ W2,
                       const float* __restrict__ W1,
                       _Float16* __restrict__ WgT_h, _Float16* __restrict__ Whh_h,
                       _Float16* __restrict__ Wih_h, _Float16* __restrict__ W2_h,
                       _Float16* __restrict__ W1_h) {
  int i = blockIdx.x*256 + threadIdx.x;
  if (i < H_*H_) { int j = i>>7, k = i&127; WgT_h[i] = (_Float16)Wg[k*H_ + j]; return; }
  i -= H_*H_;
  if (i < 3*H_*H_) { Whh_h[i] = (_Float16)Whh[i]; return; }
  i -= 3*H_*H_;
  if (i < 3*H_*H_) { Wih_h[i] = (_Float16)Wih[i]; return; }
  i -= 3*H_*H_;
  if (i < H_*H_) { W2_h[i] = (_Float16)W2[i]; return; }
  i -= H_*H_;
  if (i < H_*H_) { W1_h[i] = (_Float16)W1[i]; return; }
}

// ---------------- K2: fully-fused per-session kernel --------------------------
// Phase A (GNN step): gather emb[items] -> LDS; mgh = x @ [WgT;Whh]^T (LDS);
//   scatter-add; gi = agg @ Wih^T; GRU -> xg kept in LDS (never hits global).
// Phase B (session readout): hidden gather from LDS xg; q2 GEMM; q1 dot;
//   wave-parallel alpha; pool; hybrid; layernorm -> a_h.
// Phase-B LDS overlays the dead mgh region. Peak 74560 B -> 2 blocks/CU.
__global__ __launch_bounds__(256) void k_mega(
    const int* __restrict__ items, const int* __restrict__ edge_index,
    const int* __restrict__ sequence, const int* __restrict__ mask,
    const float* __restrict__ emb,
    const _Float16* __restrict__ Wgh, const _Float16* __restrict__ Wih,
    const _Float16* __restrict__ W2h, const _Float16* __restrict__ W1h,
    const float* __restrict__ b_ih, const float* __restrict__ b_hh,
    const float* __restrict__ b1, const float* __restrict__ b2,
    const float* __restrict__ w3, const float* __restrict__ Wt,
    const float* __restrict__ bt, const float* __restrict__ gamma,
    const float* __restrict__ beta, _Float16* __restrict__ a_h) {
  __shared__ __align__(16) char smem[74560];
  // Phase A layout
  float*    xf   = (float*)(smem);              // [16][128] fp32 x, later GRU out
  _Float16* x16  = (_Float16*)(smem + 8192);    // [16][PITCH] f16 x (MFMA A)
  float*    mghl = (float*)(smem + 12544);      // [16][MGP]  [m(128) | gh(384)]
  float*    gil  = (float*)(smem + 45568);      // [16][GILP] gi (agg aliases)
  _Float16* a16  = (_Float16*)(smem + 70208);   // [16][PITCH] f16 agg
  float*    agg  = gil;                         // dead before gil written
  // Phase B layout (overlays mghl region; xf stays live with GRU outputs)
  float*    hid    = (float*)(smem + 12544);    // [21][128] rows 0..19 hidden, 20 ht
  _Float16* h16    = (_Float16*)(smem + 23296); // [32][PITCH] f16 hidden (20..31 = 0)
  float*    qs     = (float*)(smem + 32000);    // [20][128] q2
  float*    q1full = (float*)(smem + 42240);    // [128] q1 + b1 + b2
  float*    cat    = (float*)(smem + 42752);    // [256]
  float*    alphas = (float*)(smem + 43776);    // [20]
  float*    red4   = (float*)(smem + 43856);    // [4]

  const int b = blockIdx.x, tid = threadIdx.x;
  const int w = tid >> 6, lane = tid & 63, quad = lane >> 4, r16 = lane & 15;

  // ---- A1: gather node features
  #pragma unroll
  for (int j = 0; j < 8; j++) {
    int idx = j*256 + tid;
    int n = idx >> 7, h = idx & 127;
    float v = emb[(size_t)items[b*NS_ + n]*H_ + h];
    xf[n*H_ + h] = v;
    x16[n*PITCH + h] = (_Float16)v;
  }
  __syncthreads();
  // ---- A2: mghl[16,512] = x @ Wgh[512,128]^T ; wave w owns n-tiles w*8..w*8+7
  {
    half8 afr[4];
    #pragma unroll
    for (int kk = 0; kk < 4; kk++)
      afr[kk] = *reinterpret_cast<const half8*>(&x16[r16*PITCH + kk*32 + quad*8]);
    floatx4 acc[8];
    #pragma unroll
    for (int t = 0; t < 8; t++) acc[t] = (floatx4){0.f,0.f,0.f,0.f};
    #pragma unroll
    for (int t = 0; t < 8; t++) {
      int g = w*8 + t;
      #pragma unroll
      for (int kk = 0; kk < 4; kk++) {
        half8 bfr = *reinterpret_cast<const half8*>(&Wgh[(size_t)(g*16 + r16)*H_ + kk*32 + quad*8]);
        acc[t] = __builtin_amdgcn_mfma_f32_16x16x32_f16(afr[kk], bfr, acc[t], 0, 0, 0);
      }
    }
    #pragma unroll
    for (int t = 0; t < 8; t++)
      #pragma unroll
      for (int r = 0; r < 4; r++)
        mghl[(quad*4 + r)*MGP + (w*8 + t)*16 + r16] = acc[t][r];
  }
  __syncthreads();
  // ---- A3: scatter-add m into agg; thread h owns column h (race-free)
  if (tid < 128) {
    #pragma unroll
    for (int j = 0; j < NS_; j++) agg[j*H_ + tid] = 0.f;
    for (int e = 0; e < EPS_; e++) {
      int se = edge_index[b*EPS_ + e] - b*NS_;
      int de = edge_index[N_EDGES + b*EPS_ + e] - b*NS_;
      agg[de*H_ + tid] += mghl[se*MGP + tid];
    }
  }
  __syncthreads();
  // ---- A4: agg -> f16
  #pragma unroll
  for (int j = 0; j < 8; j++) {
    int idx = j*256 + tid;
    a16[(idx >> 7)*PITCH + (idx & 127)] = (_Float16)agg[idx];
  }
  __syncthreads();
  // ---- A5: gil[16,384] = agg @ Wih[384,128]^T ; wave w owns n-tiles w*6..w*6+5
  {
    half8 afr[4];
    #pragma unroll
    for (int kk = 0; kk < 4; kk++)
      afr[kk] = *reinterpret_cast<const half8*>(&a16[r16*PITCH + kk*32 + quad*8]);
    floatx4 acc[6];
    #pragma unroll
    for (int t = 0; t < 6; t++) acc[t] = (floatx4){0.f,0.f,0.f,0.f};
    #pragma unroll
    for (int t = 0; t < 6; t++) {
      int g = w*6 + t;
      #pragma unroll
      for (int kk = 0; kk < 4; kk++) {
        half8 bfr = *reinterpret_cast<const half8*>(&Wih[(size_t)(g*16 + r16)*H_ + kk*32 + quad*8]);
        acc[t] = __builtin_amdgcn_mfma_f32_16x16x32_f16(afr[kk], bfr, acc[t], 0, 0, 0);
      }
    }
    #pragma unroll
    for (int t = 0; t < 6; t++)
      #pragma unroll
      for (int r = 0; r < 4; r++)
        gil[(quad*4 + r)*GILP + (w*6 + t)*16 + r16] = acc[t][r];
  }
  __syncthreads();
  // ---- A6: GRU epilogue -> xf in place (per-element read-then-write, no hazard)
  #pragma unroll
  for (int j = 0; j < 8; j++) {
    int idx = j*256 + tid;
    int nl = idx >> 7, h = idx & 127;
    float ir  = gil[nl*GILP + h]       + b_ih[h];
    float iz  = gil[nl*GILP + 128 + h] + b_ih[128 + h];
    float in_ = gil[nl*GILP + 256 + h] + b_ih[256 + h];
    float hr  = mghl[nl*MGP + 128 + h] + b_hh[h];
    float hz  = mghl[nl*MGP + 256 + h] + b_hh[128 + h];
    float hn  = mghl[nl*MGP + 384 + h] + b_hh[256 + h];
    float rr = 1.f/(1.f + __expf(-(ir + hr)));
    float zz = 1.f/(1.f + __expf(-(iz + hz)));
    float nn = tanhf(in_ + rr*hn);
    float hp = xf[nl*H_ + h];
    xf[nl*H_ + h] = (1.f - zz)*nn + zz*hp;
  }
  __syncthreads();
  // ---- B1: hidden gather from LDS xg (phase-B overlay of mghl begins here)
  int len = 0;
  #pragma unroll
  for (int i = 0; i < L_; i++) len += mask[b*L_ + i];
  #pragma unroll
  for (int j = 0; j < 10; j++) {
    int r = j*2 + (tid >> 7);
    int h = tid & 127;
    int seqv = sequence[b*L_ + r];
    float val = 0.f;
    if (seqv != 0) {
      int idx = -1;
      #pragma unroll
      for (int jj = 0; jj < NS_; jj++) { if (idx < 0 && items[b*NS_ + jj] == seqv) idx = jj; }
      val = (idx >= 0) ? xf[idx*H_ + h] : emb[(size_t)seqv*H_ + h];
    }
    hid[r*H_ + h] = val;
    h16[r*PITCH + h] = (_Float16)val;
  }
  #pragma unroll
  for (int j = 0; j < 6; j++) {   // zero f16 pad rows 20..31 (cols 0..127)
    int idx = j*256 + tid;
    h16[(20 + (idx >> 7))*PITCH + (idx & 127)] = (_Float16)0.f;
  }
  __syncthreads();
  if (tid < 128) hid[20*H_ + tid] = hid[(len-1)*H_ + tid];   // ht
  __syncthreads();
  // ---- B2: q2[20,128] = hidden @ W2^T (M-tile 32, N=128, K=128)
  {
    half8 afr[2][4];
    #pragma unroll
    for (int mt = 0; mt < 2; mt++)
      #pragma unroll
      for (int kk = 0; kk < 4; kk++)
        afr[mt][kk] = *reinterpret_cast<const half8*>(&h16[(mt*16 + r16)*PITCH + kk*32 + quad*8]);
    floatx4 acc[2][2];
    #pragma unroll
    for (int mt = 0; mt < 2; mt++)
      #pragma unroll
      for (int nt = 0; nt < 2; nt++) acc[mt][nt] = (floatx4){0.f,0.f,0.f,0.f};
    #pragma unroll
    for (int nt = 0; nt < 2; nt++) {
      #pragma unroll
      for (int kk = 0; kk < 4; kk++) {
        half8 bfr = *reinterpret_cast<const half8*>(&W2h[(size_t)((w*2 + nt)*16 + r16)*H_ + kk*32 + quad*8]);
        acc[0][nt] = __builtin_amdgcn_mfma_f32_16x16x32_f16(afr[0][kk], bfr, acc[0][nt], 0, 0, 0);
        acc[1][nt] = __builtin_amdgcn_mfma_f32_16x16x32_f16(afr[1][kk], bfr, acc[1][nt], 0, 0, 0);
      }
    }
    #pragma unroll
    for (int mt = 0; mt < 2; mt++)
      #pragma unroll
      for (int nt = 0; nt < 2; nt++)
        #pragma unroll
        for (int r = 0; r < 4; r++) {
          int row = mt*16 + quad*4 + r;
          if (row < 20) qs[row*H_ + (w*2 + nt)*16 + r16] = acc[mt][nt][r];
        }
  }
  // ---- B3: q1[t] = b1+b2 + ht(fp32) . W1(f16 row t)
  if (tid < 128) {
    float s = b1[tid] + b2[tid];
    const half8* wrow = reinterpret_cast<const half8*>(&W1h[(size_t)tid*H_]);
    #pragma unroll
    for (int k8 = 0; k8 < 16; k8++) {
      half8 hv = wrow[k8];
      #pragma unroll
      for (int u = 0; u < 8; u++) s += hid[20*H_ + k8*8 + u] * (float)hv[u];
    }
    q1full[tid] = s;
  }
  __syncthreads();
  // ---- B4: alpha; wave w -> positions w*5 .. w*5+4
  for (int j = 0; j < 5; j++) {
    int l = w*5 + j;
    float v = 0.f;
    #pragma unroll
    for (int p = 0; p < 2; p++) {
      int t = lane + p*64;
      float s = q1full[t] + qs[l*H_ + t];
      v += (1.f/(1.f + __expf(-s))) * w3[t];
    }
    #pragma unroll
    for (int o = 32; o > 0; o >>= 1) v += __shfl_down(v, o);
    if (lane == 0) alphas[l] = v;
  }
  __syncthreads();
  // ---- B5: attention pool + cat
  if (tid < 128) {
    float af = 0.f;
    #pragma unroll
    for (int l = 0; l < L_; l++) af += alphas[l]*hid[l*H_ + tid];
    cat[tid] = af; cat[128 + tid] = hid[20*H_ + tid];
  }
  __syncthreads();
  // ---- B6: hybrid transform + layernorm -> a_h
  float hyb = 0.f;
  if (tid < 128) {
    hyb = bt[tid];
    const float* wrow = &Wt[(size_t)tid*256];
    #pragma unroll 4
    for (int k = 0; k < 256; k++) hyb += cat[k]*wrow[k];
  }
  float s1 = (tid < 128) ? hyb : 0.f;
  #pragma unroll
  for (int o = 32; o > 0; o >>= 1) s1 += __shfl_down(s1, o);
  if (lane == 0) red4[w] = s1;
  __syncthreads();
  float mu = (red4[0] + red4[1] + red4[2] + red4[3]) * (1.f/128.f);
  __syncthreads();
  float d = (tid < 128) ? (hyb - mu) : 0.f;
  float s2 = d*d;
  #pragma unroll
  for (int o = 32; o > 0; o >>= 1) s2 += __shfl_down(s2, o);
  if (lane == 0) red4[w] = s2;
  __syncthreads();
  if (tid < 128) {
    float var = (red4[0] + red4[1] + red4[2] + red4[3]) * (1.f/128.f);
    float y = d * rsqrtf(var + 1e-5f) * gamma[tid] + beta[tid];
    a_h[(size_t)b*H_ + tid] = (_Float16)y;
  }
}

// ---------------- K3: scores = a * emb[1:]^T  [512, 99999] fp32 out --------------
// grid 1563 nt-blocks x 512 thr (8 waves). M=512 in one block: emb tile read ONCE;
// A-fragments loaded directly from L2-resident a_h (128 KB), no LDS staging for A.
__global__ __launch_bounds__(512) void k_scores(
    const _Float16* __restrict__ a_h, const float* __restrict__ emb,
    float* __restrict__ out) {
  __shared__ _Float16 lds_b[64*PITCH];
  const int tid = threadIdx.x;
  const int nt = blockIdx.x;
  // stage B: 64 emb rows fp32 -> f16 (guard last tile): 2048 float4-chunks = 4*512
  #pragma unroll
  for (int i = 0; i < 4; i++) {
    int lin = i*512 + tid;
    int row = lin >> 5, c4 = lin & 31;
    int g = nt*64 + row;
    float4 v = {0.f, 0.f, 0.f, 0.f};
    if (g < NV) v = *reinterpret_cast<const float4*>(&emb[(size_t)(1 + g)*H_ + c4*4]);
    union { _Float16 h[4]; uint2 u; } p;
    p.h[0]=(_Float16)v.x; p.h[1]=(_Float16)v.y; p.h[2]=(_Float16)v.z; p.h[3]=(_Float16)v.w;
    *reinterpret_cast<uint2*>(&lds_b[row*PITCH + c4*4]) = p.u;
  }
  __syncthreads();
  const int w = tid >> 6, lane = tid & 63, quad = lane >> 4, r16 = lane & 15;
  floatx4 acc[4][4];
  #pragma unroll
  for (int ms = 0; ms < 4; ms++)
    #pragma unroll
    for (int n4 = 0; n4 < 4; n4++) acc[ms][n4] = (floatx4){0.f,0.f,0.f,0.f};
  #pragma unroll
  for (int ms = 0; ms < 4; ms++) {
    half8 afr[4];
    #pragma unroll
    for (int kk = 0; kk < 4; kk++)
      afr[kk] = *reinterpret_cast<const half8*>(&a_h[(size_t)(w*64 + ms*16 + r16)*H_ + kk*32 + quad*8]);
    #pragma unroll
    for (int n4 = 0; n4 < 4; n4++) {
      #pragma unroll
      for (int kk = 0; kk < 4; kk++) {
        half8 bfr = *reinterpret_cast<const half8*>(&lds_b[(n4*16 + r16)*PITCH + kk*32 + quad*8]);
        acc[ms][n4] = __builtin_amdgcn_mfma_f32_16x16x32_f16(afr[kk], bfr, acc[ms][n4], 0, 0, 0);
      }
    }
  }
  #pragma unroll
  for (int ms = 0; ms < 4; ms++)
    #pragma unroll
    for (int n4 = 0; n4 < 4; n4++)
      #pragma unroll
      for (int r = 0; r < 4; r++) {
        int row = w*64 + ms*16 + quad*4 + r;
        int col = nt*64 + n4*16 + r16;
        if (col < NV) out[(size_t)row*NV + col] = acc[ms][n4][r];
      }
}

extern "C" void kernel_launch(void* const* d_in, const int* in_sizes, int n_in,
                              void* d_out, int out_size, void* d_ws, size_t ws_size,
                              hipStream_t stream) {
  const int*   items     = (const int*)d_in[0];
  const int*   edge_index= (const int*)d_in[1];
  const int*   sequence  = (const int*)d_in[2];
  const int*   mask      = (const int*)d_in[3];
  const float* emb       = (const float*)d_in[4];
  const float* ggnn_w    = (const float*)d_in[5];
  const float* W_ih      = (const float*)d_in[6];
  const float* W_hh      = (const float*)d_in[7];
  const float* b_ih      = (const float*)d_in[8];
  const float* b_hh      = (const float*)d_in[9];
  const float* W1        = (const float*)d_in[10];
  const float* b1        = (const float*)d_in[11];
  const float* W2        = (const float*)d_in[12];
  const float* b2        = (const float*)d_in[13];
  const float* w3        = (const float*)d_in[14];
  const float* Wt        = (const float*)d_in[15];
  const float* bt        = (const float*)d_in[16];
  const float* gamma     = (const float*)d_in[17];
  const float* beta      = (const float*)d_in[18];

  char* ws = (char*)d_ws;
  _Float16* a_h   = (_Float16*)(ws + 39059456);
  _Float16* WgT_h = (_Float16*)(ws + 39190528);
  _Float16* Whh_h = (_Float16*)(ws + 39223296); // contiguous after WgT_h ([WgT;Whh])
  _Float16* Wih_h = (_Float16*)(ws + 39321600);
  _Float16* W2_h  = (_Float16*)(ws + 39419904);
  _Float16* W1_h  = (_Float16*)(ws + 39452672);
  float* out = (float*)d_out;

  // K1: f16 weight conversions (147456 elems = 576*256)
  k_prep<<<576, 256, 0, stream>>>(ggnn_w, W_hh, W_ih, W2, W1,
                                  WgT_h, Whh_h, Wih_h, W2_h, W1_h);
  // K2: fully-fused per-session GNN + readout (xg never leaves LDS)
  k_mega<<<512, 256, 0, stream>>>(items, edge_index, sequence, mask, emb,
                                  WgT_h, Wih_h, W2_h, W1_h, b_ih, b_hh,
                                  b1, b2, w3, Wt, bt, gamma, beta, a_h);
  // K3: scores = a * emb[1:]^T (single-pass M=512, emb read once)
  k_scores<<<1563, 512, 0, stream>>>(a_h, emb, out);
}